// Round 8
// baseline (2249.167 us; speedup 1.0000x reference)
//
#include <hip/hip_runtime.h>
#include <cstddef>
#include <cstdint>

// Model dims
#define HD    768
#define ID    1536
#define ND    16
#define KD    4
#define RD    48
#define NLAY  8
#define BB    4
#define LL    1024
#define BL    4096   // BB*LL
#define DIN   13
#define DA_   128
#define RP_   4

// scan chunking
#define NC    32
#define CS    32     // LL/NC

typedef _Float16 f16;
typedef f16 f16x8 __attribute__((ext_vector_type(8)));
typedef float f32x4 __attribute__((ext_vector_type(4)));

__device__ __forceinline__ float softplus_f(float x) {
    return (x > 20.f) ? x : log1pf(expf(x));
}

__device__ __forceinline__ float fast_exp2(float x) {
#if __has_builtin(__builtin_amdgcn_exp2f)
    return __builtin_amdgcn_exp2f(x);
#else
    return exp2f(x);
#endif
}

// ---------------- fp32 -> f16 cast ----------------
__global__ __launch_bounds__(256) void cast_f16_k(
    const float* __restrict__ in, f16* __restrict__ out, int n)
{
    int i = (blockIdx.x * 256 + threadIdx.x) * 4;
    if (i + 3 < n) {
        float4 v = *(const float4*)(in + i);
        out[i]     = (f16)v.x;
        out[i + 1] = (f16)v.y;
        out[i + 2] = (f16)v.z;
        out[i + 3] = (f16)v.w;
    } else {
        for (int j = i; j < n; ++j) out[j] = (f16)in[j];
    }
}

// dt_w (NL*1536 rows of 48) -> padded (rows of 64, zeros at k>=48)
__global__ __launch_bounds__(256) void cast_dtw_k(
    const float* __restrict__ in, f16* __restrict__ out)
{
    int idx = blockIdx.x * 256 + threadIdx.x;
    if (idx >= NLAY * ID * 64) return;
    int k = idx & 63, r = idx >> 6;
    out[idx] = (k < RD) ? (f16)in[r * RD + k] : (f16)0.f;
}

// ---------------- zero fill ----------------
__global__ __launch_bounds__(256) void zero_k(float* __restrict__ p, int n)
{
    int i = blockIdx.x * 256 + threadIdx.x;
    if (i < n) p[i] = 0.f;
}

// ---------------- epilogue helper ----------------
__device__ __forceinline__ void epilogue_store(
    float v, int row, int col, int N,
    const float* __restrict__ res, int ldres,
    float* __restrict__ C, int ldc,
    f16* __restrict__ Cb, int ldcb, int ncb, int act,
    const float* __restrict__ bias)
{
    if (col >= N) return;
    if (bias) v += bias[col];
    if (act == 1) v = fmaxf(v, 0.f);
    else if (act == 2) v = tanhf(v);
    else if (act == 3) v = softplus_f(v);
    if (res) v += res[(size_t)row * ldres + col];
    if (C) C[(size_t)row * ldc + col] = v;
    if (Cb && col < ncb) Cb[(size_t)row * ldcb + col] = (f16)v;
}

__device__ __forceinline__ void async_copy16(const f16* g, f16* l) {
    __builtin_amdgcn_global_load_lds(
        (const __attribute__((address_space(1))) void*)g,
        (__attribute__((address_space(3))) void*)l, 16, 0, 0);
}

// ---------------- f16 MFMA GEMM, 128x128 tile, BK=32, double-buffered ------
// Prefetch tile k+1 after the barrier; barrier's vmcnt(0) then waits on
// loads issued one full iteration earlier (latency hidden).
__global__ __launch_bounds__(256) void hgemm_k(
    const f16* __restrict__ A, int lda,
    const f16* __restrict__ W, int ldw,
    const float* __restrict__ bias,
    const float* __restrict__ res, int ldres,
    float* __restrict__ C, int ldc,
    f16* __restrict__ Cb, int ldcb, int ncb,
    int M, int N, int K, int act)
{
    __shared__ f16 As[2][128 * 32];
    __shared__ f16 Bs[2][128 * 32];
    int tid = threadIdx.x;
    int wave = tid >> 6, lane = tid & 63;
    int m0 = blockIdx.y * 128, n0 = blockIdx.x * 128;

    int wm = wave & 1, wn = wave >> 1;
    int lm = lane & 15;
    int kq = (lane >> 4) * 8;

    int srow = lane >> 2;
    int skc  = (lane & 3) * 8;

    f32x4 acc[4][4] = {};

    int nIter = K >> 5;

    // prefetch tile 0 -> buf 0
#pragma unroll
    for (int it = 0; it < 2; ++it) {
        int c16 = wave + it * 4;
        int row = c16 * 16 + srow;
        async_copy16(A + (size_t)(m0 + row) * lda + skc, As[0] + c16 * 512);
        async_copy16(W + (size_t)(n0 + row) * ldw + skc, Bs[0] + c16 * 512);
    }

    for (int i = 0; i < nIter; ++i) {
        __syncthreads();   // drains vmcnt: buf(i&1) ready; prev reads done
        if (i + 1 < nIter) {
            int k0 = (i + 1) << 5;
            int nb = (i + 1) & 1;
#pragma unroll
            for (int it = 0; it < 2; ++it) {
                int c16 = wave + it * 4;
                int row = c16 * 16 + srow;
                async_copy16(A + (size_t)(m0 + row) * lda + k0 + skc,
                             As[nb] + c16 * 512);
                async_copy16(W + (size_t)(n0 + row) * ldw + k0 + skc,
                             Bs[nb] + c16 * 512);
            }
        }
        const f16* ab = As[i & 1];
        const f16* bb = Bs[i & 1];
        f16x8 af[4], bf[4];
#pragma unroll
        for (int mt = 0; mt < 4; ++mt)
            af[mt] = *(const f16x8*)(ab + (wm * 64 + mt * 16 + lm) * 32 + kq);
#pragma unroll
        for (int nt = 0; nt < 4; ++nt)
            bf[nt] = *(const f16x8*)(bb + (wn * 64 + nt * 16 + lm) * 32 + kq);
#pragma unroll
        for (int mt = 0; mt < 4; ++mt)
#pragma unroll
            for (int nt = 0; nt < 4; ++nt)
                acc[mt][nt] = __builtin_amdgcn_mfma_f32_16x16x32_f16(
                    af[mt], bf[nt], acc[mt][nt], 0, 0, 0);
    }

    int rq = (lane >> 4) * 4;
#pragma unroll
    for (int mt = 0; mt < 4; ++mt)
#pragma unroll
        for (int nt = 0; nt < 4; ++nt) {
            int col = n0 + wn * 64 + nt * 16 + lm;
#pragma unroll
            for (int r = 0; r < 4; ++r) {
                int row = m0 + wm * 64 + mt * 16 + rq + r;
                epilogue_store(acc[mt][nt][r], row, col, N, res, ldres,
                               C, ldc, Cb, ldcb, ncb, act, bias);
            }
        }
}

// ---------------- f16 MFMA GEMM, 64x64 tile, BK=64, double-buffered --------
__global__ __launch_bounds__(256) void hgemm64_k(
    const f16* __restrict__ A, int lda,
    const f16* __restrict__ W, int ldw,
    const float* __restrict__ bias,
    const float* __restrict__ res, int ldres,
    float* __restrict__ C, int ldc,
    f16* __restrict__ Cb, int ldcb, int ncb,
    int M, int N, int K, int act)
{
    __shared__ f16 As[2][64 * 64];
    __shared__ f16 Bs[2][64 * 64];
    int tid = threadIdx.x;
    int wave = tid >> 6, lane = tid & 63;
    int m0 = blockIdx.y * 64, n0 = blockIdx.x * 64;

    int wm = wave & 1, wn = wave >> 1;
    int lm = lane & 15;
    int kq = (lane >> 4) * 8;

    int srow = tid >> 2;
    int skc  = (tid & 3) * 8;

    f32x4 acc[2][2] = {};
    int nIter = K >> 6;

#pragma unroll
    for (int it = 0; it < 2; ++it) {
        int kk   = it * 32 + skc;
        int base = it * 2048 + wave * 512;
        async_copy16(A + (size_t)(m0 + srow) * lda + kk, As[0] + base);
        async_copy16(W + (size_t)(n0 + srow) * ldw + kk, Bs[0] + base);
    }

    for (int i = 0; i < nIter; ++i) {
        __syncthreads();
        if (i + 1 < nIter) {
            int k0 = (i + 1) << 6;
            int nb = (i + 1) & 1;
#pragma unroll
            for (int it = 0; it < 2; ++it) {
                int kk   = it * 32 + skc;
                int base = it * 2048 + wave * 512;
                async_copy16(A + (size_t)(m0 + srow) * lda + k0 + kk,
                             As[nb] + base);
                async_copy16(W + (size_t)(n0 + srow) * ldw + k0 + kk,
                             Bs[nb] + base);
            }
        }
        const f16* ab = As[i & 1];
        const f16* bb = Bs[i & 1];
        f16x8 af[2][2], bf[2][2];
#pragma unroll
        for (int ks = 0; ks < 2; ++ks) {
#pragma unroll
            for (int mt = 0; mt < 2; ++mt)
                af[mt][ks] = *(const f16x8*)(ab + ks * 2048 +
                                 (wm * 32 + mt * 16 + lm) * 32 + kq);
#pragma unroll
            for (int nt = 0; nt < 2; ++nt)
                bf[nt][ks] = *(const f16x8*)(bb + ks * 2048 +
                                 (wn * 32 + nt * 16 + lm) * 32 + kq);
        }
#pragma unroll
        for (int ks = 0; ks < 2; ++ks)
#pragma unroll
            for (int mt = 0; mt < 2; ++mt)
#pragma unroll
                for (int nt = 0; nt < 2; ++nt)
                    acc[mt][nt] = __builtin_amdgcn_mfma_f32_16x16x32_f16(
                        af[mt][ks], bf[nt][ks], acc[mt][nt], 0, 0, 0);
    }

    int rq = (lane >> 4) * 4;
#pragma unroll
    for (int mt = 0; mt < 2; ++mt)
#pragma unroll
        for (int nt = 0; nt < 2; ++nt) {
            int col = n0 + wn * 32 + nt * 16 + lm;
#pragma unroll
            for (int r = 0; r < 4; ++r) {
                int row = m0 + wm * 32 + mt * 16 + rq + r;
                epilogue_store(acc[mt][nt][r], row, col, N, res, ldres,
                               C, ldc, Cb, ldcb, ncb, act, bias);
            }
        }
}

// ---------------- x_proj split-K GEMM: 64x64 tile, dbuf, fp32 partials -----
__global__ __launch_bounds__(256) void hgemm64s_k(
    const f16* __restrict__ A, int lda,
    const f16* __restrict__ W, int ldw,
    float* __restrict__ Cp, int ldc, size_t PS,
    int N, int kPer)
{
    __shared__ f16 As[2][64 * 64];
    __shared__ f16 Bs[2][64 * 64];
    int tid = threadIdx.x;
    int wave = tid >> 6, lane = tid & 63;
    int m0 = blockIdx.y * 64, n0 = blockIdx.x * 64;
    int z = blockIdx.z;
    int kbeg = z * kPer;

    int wm = wave & 1, wn = wave >> 1;
    int lm = lane & 15;
    int kq = (lane >> 4) * 8;
    int srow = tid >> 2;
    int skc  = (tid & 3) * 8;

    f32x4 acc[2][2] = {};
    int nIter = kPer >> 6;

#pragma unroll
    for (int it = 0; it < 2; ++it) {
        int kk   = it * 32 + skc;
        int base = it * 2048 + wave * 512;
        async_copy16(A + (size_t)(m0 + srow) * lda + kbeg + kk, As[0] + base);
        async_copy16(W + (size_t)(n0 + srow) * ldw + kbeg + kk, Bs[0] + base);
    }

    for (int i = 0; i < nIter; ++i) {
        __syncthreads();
        if (i + 1 < nIter) {
            int k0 = kbeg + ((i + 1) << 6);
            int nb = (i + 1) & 1;
#pragma unroll
            for (int it = 0; it < 2; ++it) {
                int kk   = it * 32 + skc;
                int base = it * 2048 + wave * 512;
                async_copy16(A + (size_t)(m0 + srow) * lda + k0 + kk,
                             As[nb] + base);
                async_copy16(W + (size_t)(n0 + srow) * ldw + k0 + kk,
                             Bs[nb] + base);
            }
        }
        const f16* ab = As[i & 1];
        const f16* bb = Bs[i & 1];
        f16x8 af[2][2], bf[2][2];
#pragma unroll
        for (int ks = 0; ks < 2; ++ks) {
#pragma unroll
            for (int mt = 0; mt < 2; ++mt)
                af[mt][ks] = *(const f16x8*)(ab + ks * 2048 +
                                 (wm * 32 + mt * 16 + lm) * 32 + kq);
#pragma unroll
            for (int nt = 0; nt < 2; ++nt)
                bf[nt][ks] = *(const f16x8*)(bb + ks * 2048 +
                                 (wn * 32 + nt * 16 + lm) * 32 + kq);
        }
#pragma unroll
        for (int ks = 0; ks < 2; ++ks)
#pragma unroll
            for (int mt = 0; mt < 2; ++mt)
#pragma unroll
                for (int nt = 0; nt < 2; ++nt)
                    acc[mt][nt] = __builtin_amdgcn_mfma_f32_16x16x32_f16(
                        af[mt][ks], bf[nt][ks], acc[mt][nt], 0, 0, 0);
    }

    float* C = Cp + (size_t)z * PS;
    int rq = (lane >> 4) * 4;
#pragma unroll
    for (int mt = 0; mt < 2; ++mt)
#pragma unroll
        for (int nt = 0; nt < 2; ++nt) {
            int col = n0 + wn * 32 + nt * 16 + lm;
            if (col >= N) continue;
#pragma unroll
            for (int r = 0; r < 4; ++r) {
                int row = m0 + wm * 32 + mt * 16 + rq + r;
                C[(size_t)row * ldc + col] = acc[mt][nt][r];
            }
        }
}

// combine 4 x_proj partials -> ssm fp32 + ssmb f16 (48 cols + 16 zero pad)
__global__ __launch_bounds__(256) void xcomb_k(
    const float* __restrict__ part, float* __restrict__ ssm,
    f16* __restrict__ ssmb)
{
    int idx = blockIdx.x * 256 + threadIdx.x;   // over BL*96
    if (idx >= BL * 96) return;
    int row = idx / 96, c = idx % 96;
    const size_t PS = (size_t)BL * 80;
    if (c < 80) {
        size_t o = (size_t)row * 80 + c;
        float s = part[o] + part[PS + o] + part[2 * PS + o] + part[3 * PS + o];
        ssm[o] = s;
        if (c < RD) ssmb[(size_t)row * 64 + c] = (f16)s;
    } else {
        ssmb[(size_t)row * 64 + (c - 80 + RD)] = (f16)0.f;
    }
}

// ---------------- fp32 tiled GEMM (small-K cases) ----------------
#define BM 64
#define BN 64
#define BKK 16
__global__ __launch_bounds__(256) void gemm_k(
    const float* __restrict__ A, int lda,
    const float* __restrict__ W,
    const float* __restrict__ bias,
    float* __restrict__ C, int ldc,
    f16* __restrict__ Cb, int ldcb,
    int M, int N, int K, int act)
{
    __shared__ float As[BKK][BM + 4];
    __shared__ float Ws[BKK][BN + 4];
    int tid = threadIdx.x;
    int tx = tid & 15, ty = tid >> 4;
    int m0 = blockIdx.y * BM, n0 = blockIdx.x * BN;
    float acc[4][4] = {};
    int arow = tid >> 2;
    int acol = (tid & 3) * 4;

    for (int k0 = 0; k0 < K; k0 += BKK) {
        int gm = m0 + arow;
        int gn = n0 + arow;
#pragma unroll
        for (int j = 0; j < 4; ++j) {
            int gk = k0 + acol + j;
            float av = 0.f, wv = 0.f;
            if (gm < M && gk < K) av = A[(size_t)gm * lda + gk];
            if (gn < N && gk < K) wv = W[(size_t)gn * K + gk];
            As[acol + j][arow] = av;
            Ws[acol + j][arow] = wv;
        }
        __syncthreads();
#pragma unroll
        for (int k = 0; k < BKK; ++k) {
            float a[4], b[4];
#pragma unroll
            for (int i = 0; i < 4; ++i) a[i] = As[k][ty * 4 + i];
#pragma unroll
            for (int j = 0; j < 4; ++j) b[j] = Ws[k][tx * 4 + j];
#pragma unroll
            for (int i = 0; i < 4; ++i)
#pragma unroll
                for (int j = 0; j < 4; ++j)
                    acc[i][j] += a[i] * b[j];
        }
        __syncthreads();
    }

#pragma unroll
    for (int i = 0; i < 4; ++i) {
        int row = m0 + ty * 4 + i;
        if (row >= M) continue;
#pragma unroll
        for (int j = 0; j < 4; ++j) {
            int col = n0 + tx * 4 + j;
            if (col >= N) continue;
            float v = acc[i][j];
            if (bias) v += bias[col];
            if (act == 1) v = fmaxf(v, 0.f);
            if (C) C[(size_t)row * ldc + col] = v;
            if (Cb) Cb[(size_t)row * ldcb + col] = (f16)v;
        }
    }
}

// ---------------- RMSNorm over 768, f16 out ----------------
__global__ __launch_bounds__(256) void rmsnorm_k(
    const float* __restrict__ x, const float* __restrict__ w,
    f16* __restrict__ out)
{
    int row = blockIdx.x;
    const float* xr = x + (size_t)row * HD;
    int tid = threadIdx.x;
    float v0 = xr[tid], v1 = xr[tid + 256], v2 = xr[tid + 512];
    __shared__ float red[256];
    red[tid] = v0 * v0 + v1 * v1 + v2 * v2;
    __syncthreads();
    for (int o = 128; o; o >>= 1) {
        if (tid < o) red[tid] += red[tid + o];
        __syncthreads();
    }
    float scale = rsqrtf(red[0] / (float)HD + 1e-5f);
    f16* outr = out + (size_t)row * HD;
    outr[tid]       = (f16)(v0 * scale * w[tid]);
    outr[tid + 256] = (f16)(v1 * scale * w[tid + 256]);
    outr[tid + 512] = (f16)(v2 * scale * w[tid + 512]);
}

// ---------------- Causal depthwise conv (K=4) + bias + SiLU, x8 vector ------
__global__ __launch_bounds__(256) void conv_silu_k(
    const f16* __restrict__ projb, const float* __restrict__ cw,
    const float* __restrict__ cb, f16* __restrict__ ub)
{
    int idx = blockIdx.x * 256 + threadIdx.x;   // over BL*ID/8
    if (idx >= BL * (ID / 8)) return;
    int i8  = (idx % (ID / 8)) * 8;
    int row = idx / (ID / 8);
    int t = row & (LL - 1);

    float4 wv[8];
#pragma unroll
    for (int j = 0; j < 8; ++j)
        wv[j] = *(const float4*)(cw + (i8 + j) * KD);

    float s[8];
    float4 cb0 = *(const float4*)(cb + i8);
    float4 cb1 = *(const float4*)(cb + i8 + 4);
    s[0] = cb0.x; s[1] = cb0.y; s[2] = cb0.z; s[3] = cb0.w;
    s[4] = cb1.x; s[5] = cb1.y; s[6] = cb1.z; s[7] = cb1.w;

#pragma unroll
    for (int k = 0; k < KD; ++k) {
        int tt = t - (KD - 1) + k;
        if (tt < 0) continue;
        f16x8 p = *(const f16x8*)(projb + (size_t)(row - (KD - 1) + k) * (2 * ID) + i8);
#pragma unroll
        for (int j = 0; j < 8; ++j) {
            float wk = (k == 0) ? wv[j].x : (k == 1) ? wv[j].y
                     : (k == 2) ? wv[j].z : wv[j].w;
            s[j] += (float)p[j] * wk;
        }
    }
    f16x8 o;
#pragma unroll
    for (int j = 0; j < 8; ++j) {
        float v = s[j] / (1.f + expf(-s[j]));
        o[j] = (f16)v;
    }
    *(f16x8*)(ub + (size_t)row * ID + i8) = o;
}

// ---------------- Selective scan: chunked two-pass ----------------
__global__ __launch_bounds__(256) void scan1_k(
    const f16*   __restrict__ dtf,   // (BL,ID)
    const float* __restrict__ ssm,   // (BL,80): B at +48
    const f16*   __restrict__ ub,    // (BL,ID)
    const float* __restrict__ A_log, // (ID,16)
    float* __restrict__ Pw, float* __restrict__ Hw)
{
    int b = blockIdx.z, c = blockIdx.y;
    int i = blockIdx.x * 256 + threadIdx.x;
    __shared__ float sB[CS * 16];
    for (int idx = threadIdx.x; idx < CS * 16; idx += 256) {
        int t = idx >> 4, n = idx & 15;
        sB[idx] = ssm[((size_t)(b * LL + c * CS + t)) * 80 + 48 + n];
    }
    __syncthreads();

    float Ain[16];
#pragma unroll
    for (int n = 0; n < 16; ++n)
        Ain[n] = -expf(A_log[i * ND + n]) * 1.44269504f;

    float h[16];
    float sdt = 0.f;
#pragma unroll
    for (int n = 0; n < 16; ++n) h[n] = 0.f;

    for (int t = 0; t < CS; ++t) {
        size_t row = (size_t)(b * LL + c * CS + t);
        float dtv = (float)dtf[row * ID + i];
        float x = dtv * (float)ub[row * ID + i];
        sdt += dtv;
        const float4* Bv = (const float4*)(sB + t * 16);
        float4 B0 = Bv[0], B1 = Bv[1], B2 = Bv[2], B3 = Bv[3];
        float Bf[16] = {B0.x, B0.y, B0.z, B0.w, B1.x, B1.y, B1.z, B1.w,
                        B2.x, B2.y, B2.z, B2.w, B3.x, B3.y, B3.z, B3.w};
#pragma unroll
        for (int n = 0; n < 16; ++n) {
            float dA = fast_exp2(dtv * Ain[n]);
            h[n] = dA * h[n] + x * Bf[n];
        }
    }
    size_t off = (((size_t)(b * NC + c) * ID + i) << 4);
    float4* pw = (float4*)(Pw + off);
    float4* hw = (float4*)(Hw + off);
#pragma unroll
    for (int q = 0; q < 4; ++q) {
        pw[q] = make_float4(fast_exp2(sdt * Ain[q*4]),
                            fast_exp2(sdt * Ain[q*4+1]),
                            fast_exp2(sdt * Ain[q*4+2]),
                            fast_exp2(sdt * Ain[q*4+3]));
        hw[q] = make_float4(h[q*4], h[q*4+1], h[q*4+2], h[q*4+3]);
    }
}

__global__ __launch_bounds__(256) void scan_comb_k(
    const float* __restrict__ Pw, float* __restrict__ Hw)
{
    int idx = blockIdx.x * 256 + threadIdx.x;   // over BB*ID*16
    int rem = idx & (ID * 16 - 1);
    int b = idx / (ID * 16);
    size_t base = (size_t)b * NC * ID * 16 + rem;
    float e = 0.f;
    for (int c = 0; c < NC; ++c) {
        size_t off = base + (size_t)c * ID * 16;
        float Hc = Hw[off];
        float Pc = Pw[off];
        Hw[off] = e;
        e = Hc + Pc * e;
    }
}

__global__ __launch_bounds__(256) void scan2_k(
    const f16*   __restrict__ dtf,
    const float* __restrict__ ssm,   // B at +48, C at +64
    const f16*   __restrict__ ub,
    const f16*   __restrict__ projb, // gate at +ID
    const float* __restrict__ A_log,
    const float* __restrict__ D,
    const float* __restrict__ Hw,    // entry states
    f16* __restrict__ y)
{
    int b = blockIdx.z, c = blockIdx.y;
    int i = blockIdx.x * 256 + threadIdx.x;
    __shared__ float sB[CS * 16];
    __shared__ float sC[CS * 16];
    for (int idx = threadIdx.x; idx < CS * 16; idx += 256) {
        int t = idx >> 4, n = idx & 15;
        size_t row = (size_t)(b * LL + c * CS + t);
        sB[idx] = ssm[row * 80 + 48 + n];
        sC[idx] = ssm[row * 80 + 64 + n];
    }
    __syncthreads();

    float Ain[16];
#pragma unroll
    for (int n = 0; n < 16; ++n)
        Ain[n] = -expf(A_log[i * ND + n]) * 1.44269504f;
    float Dv = D[i];

    float h[16];
    size_t off = (((size_t)(b * NC + c) * ID + i) << 4);
    const float4* hw = (const float4*)(Hw + off);
#pragma unroll
    for (int q = 0; q < 4; ++q) {
        float4 v = hw[q];
        h[q*4] = v.x; h[q*4+1] = v.y; h[q*4+2] = v.z; h[q*4+3] = v.w;
    }

    for (int t = 0; t < CS; ++t) {
        size_t row = (size_t)(b * LL + c * CS + t);
        float dtv = (float)dtf[row * ID + i];
        float uv  = (float)ub[row * ID + i];
        float g   = (float)projb[row * (2 * ID) + ID + i];
        float x = dtv * uv;
        const float4* Bv = (const float4*)(sB + t * 16);
        const float4* Cv = (const float4*)(sC + t * 16);
        float4 B0 = Bv[0], B1 = Bv[1], B2 = Bv[2], B3 = Bv[3];
        float4 C0 = Cv[0], C1 = Cv[1], C2 = Cv[2], C3 = Cv[3];
        float Bf[16] = {B0.x, B0.y, B0.z, B0.w, B1.x, B1.y, B1.z, B1.w,
                        B2.x, B2.y, B2.z, B2.w, B3.x, B3.y, B3.z, B3.w};
        float Cf[16] = {C0.x, C0.y, C0.z, C0.w, C1.x, C1.y, C1.z, C1.w,
                        C2.x, C2.y, C2.z, C2.w, C3.x, C3.y, C3.z, C3.w};
        float yv = 0.f;
#pragma unroll
        for (int n = 0; n < 16; ++n) {
            float dA = fast_exp2(dtv * Ain[n]);
            h[n] = dA * h[n] + x * Bf[n];
            yv += h[n] * Cf[n];
        }
        yv = (yv + uv * Dv) * (g / (1.f + expf(-g)));
        y[row * ID + i] = (f16)yv;
    }
}

// ---------------- Softmax over L per (b,r) ----------------
__global__ __launch_bounds__(256) void softmax_k(
    const float* __restrict__ s, float* __restrict__ attn)
{
    int b = blockIdx.x >> 2, r = blockIdx.x & 3;
    int tid = threadIdx.x;
    __shared__ float red[256];
    float mx = -1e30f;
    for (int j = 0; j < 4; ++j) {
        int t = tid + j * 256;
        mx = fmaxf(mx, s[((size_t)(b * LL + t)) * RP_ + r]);
    }
    red[tid] = mx;
    __syncthreads();
    for (int o = 128; o; o >>= 1) {
        if (tid < o) red[tid] = fmaxf(red[tid], red[tid + o]);
        __syncthreads();
    }
    mx = red[0];
    __syncthreads();
    float ev[4], sum = 0.f;
    for (int j = 0; j < 4; ++j) {
        int t = tid + j * 256;
        ev[j] = expf(s[((size_t)(b * LL + t)) * RP_ + r] - mx);
        sum += ev[j];
    }
    red[tid] = sum;
    __syncthreads();
    for (int o = 128; o; o >>= 1) {
        if (tid < o) red[tid] += red[tid + o];
        __syncthreads();
    }
    float inv = 1.f / red[0];
    for (int j = 0; j < 4; ++j) {
        int t = tid + j * 256;
        attn[((size_t)(b * LL + t)) * RP_ + r] = ev[j] * inv;
    }
}

// ---------------- attn pool: chunk-parallel + atomics ----------------
__global__ __launch_bounds__(256) void pool_k(
    const float* __restrict__ attn, const f16* __restrict__ hn,
    float* __restrict__ m)
{
    int br = blockIdx.x;
    int b = br >> 2, r = br & 3;
    int t0 = blockIdx.y * 64;
    int tid = threadIdx.x;
    float acc0 = 0.f, acc1 = 0.f, acc2 = 0.f;
    for (int t = t0; t < t0 + 64; ++t) {
        float w = attn[((size_t)(b * LL + t)) * RP_ + r];
        const f16* hr = hn + ((size_t)(b * LL + t)) * HD;
        acc0 += w * (float)hr[tid];
        acc1 += w * (float)hr[tid + 256];
        acc2 += w * (float)hr[tid + 512];
    }
    float* outp = m + ((size_t)(b * RP_ + r)) * HD;
    atomicAdd(outp + tid, acc0);
    atomicAdd(outp + tid + 256, acc1);
    atomicAdd(outp + tid + 512, acc2);
}

// ---------------- small GEMV ----------------
__global__ __launch_bounds__(64) void gemv_k(
    const float* __restrict__ A, int lda,
    const float* __restrict__ W, const float* __restrict__ bias,
    float* __restrict__ C, int ldc, int K, int relu)
{
    int n = blockIdx.x, b = blockIdx.y;
    int lane = threadIdx.x;
    const float* a = A + (size_t)b * lda;
    const float* w = W + (size_t)n * K;
    float s = 0.f;
    for (int k = lane; k < K; k += 64) s += a[k] * w[k];
    for (int off = 32; off; off >>= 1) s += __shfl_down(s, off);
    if (lane == 0) {
        float v = s + (bias ? bias[n] : 0.f);
        if (relu) v = fmaxf(v, 0.f);
        C[(size_t)b * ldc + n] = v;
    }
}

extern "C" void kernel_launch(void* const* d_in, const int* in_sizes, int n_in,
                              void* d_out, int out_size, void* d_ws, size_t ws_size,
                              hipStream_t stream) {
    const float* x          = (const float*)d_in[0];
    const float* mlp_in_w1  = (const float*)d_in[1];
    const float* mlp_in_b1  = (const float*)d_in[2];
    const float* mlp_in_w2  = (const float*)d_in[3];
    const float* mlp_in_b2  = (const float*)d_in[4];
    const float* mlp_in_w3  = (const float*)d_in[5];
    const float* mlp_in_b3  = (const float*)d_in[6];
    const float* norm_w     = (const float*)d_in[7];
    const float* in_proj_w  = (const float*)d_in[8];
    const float* conv_w     = (const float*)d_in[9];
    const float* conv_b     = (const float*)d_in[10];
    const float* x_proj_w   = (const float*)d_in[11];
    const float* dt_w       = (const float*)d_in[12];
    const float* dt_b       = (const float*)d_in[13];
    const float* A_log      = (const float*)d_in[14];
    const float* Dp         = (const float*)d_in[15];
    const float* out_proj_w = (const float*)d_in[16];
    const float* norm_f_w   = (const float*)d_in[17];
    const float* attn_ws1   = (const float*)d_in[18];
    const float* attn_ws2   = (const float*)d_in[19];
    const float* mlp_out_w1 = (const float*)d_in[20];
    const float* mlp_out_b1 = (const float*)d_in[21];
    const float* mlp_out_w2 = (const float*)d_in[22];
    const float* mlp_out_b2 = (const float*)d_in[23];
    const float* mlp_out_w3 = (const float*)d_in[24];
    const float* mlp_out_b3 = (const float*)d_in[25];
    float* out = (float*)d_out;

    // ---- workspace layout ----
    float* ws    = (float*)d_ws;
    float* h     = ws;                        // 4096*768
    float* ssm   = h    + (size_t)BL * HD;    // 4096*80
    float* xpart = ssm  + (size_t)BL * 80;    // 4 * 4096*80
    float* h1a   = xpart+ (size_t)4 * BL * 80;// 4096*128
    float* sbuf  = h1a  + (size_t)BL * DA_;   // 4096*4
    float* attn  = sbuf + (size_t)BL * 4;     // 4096*4
    float* mbuf  = attn + (size_t)BL * 4;     // 4*4*768
    float* o1    = mbuf + (size_t)BB * RP_ * HD;
    float* o2    = o1   + (size_t)BB * 256;
    float* Pw    = o2   + (size_t)BB * 256;   // 4*32*1536*16
    float* Hw    = Pw   + (size_t)BB * NC * ID * 16;
    f16* fb    = (f16*)(Hw + (size_t)BB * NC * ID * 16);
    f16* h1b   = fb;                          // 4096*256
    f16* h2b   = h1b  + (size_t)BL * 256;     // 4096*256
    f16* hnb   = h2b  + (size_t)BL * 256;     // 4096*768
    f16* projb = hnb  + (size_t)BL * HD;      // 4096*3072
    f16* ub    = projb+ (size_t)BL * 2 * ID;  // 4096*1536
    f16* ssmb  = ub   + (size_t)BL * ID;      // 4096*64
    f16* dtf   = ssmb + (size_t)BL * 64;      // 4096*1536
    f16* ybb   = dtf  + (size_t)BL * ID;      // 4096*1536
    f16* opwf  = ybb  + (size_t)BL * ID;      // 8*768*1536
    f16* xpwf  = opwf + (size_t)NLAY * HD * ID;
    f16* dwwf  = xpwf + (size_t)NLAY * 80 * ID;
    f16* w2f   = dwwf + (size_t)NLAY * ID * 64;
    f16* w3f   = w2f  + 256 * 256;
    f16* a1f   = w3f  + HD * 256;
    f16* ipwf  = a1f  + DA_ * HD;             // 1 or 8 slots, LAST

    size_t used_bytes = (size_t)((char*)(ipwf) - (char*)d_ws);
    size_t slot_bytes = (size_t)2 * ID * HD * sizeof(f16);
    int full = (ws_size >= used_bytes + (size_t)NLAY * slot_bytes) ? 1 : 0;

    dim3 blk(256);
    auto cgrid = [](int n) { return dim3((n / 4 + 255) / 256); };

    // ---- weight casts ----
    cast_f16_k<<<cgrid(256 * 256), blk, 0, stream>>>(mlp_in_w2, w2f, 256 * 256);
    cast_f16_k<<<cgrid(HD * 256), blk, 0, stream>>>(mlp_in_w3, w3f, HD * 256);
    cast_f16_k<<<cgrid(DA_ * HD), blk, 0, stream>>>(attn_ws1, a1f, DA_ * HD);
    cast_f16_k<<<cgrid(NLAY * HD * ID), blk, 0, stream>>>(out_proj_w, opwf, NLAY * HD * ID);
    cast_f16_k<<<cgrid(NLAY * 80 * ID), blk, 0, stream>>>(x_proj_w, xpwf, NLAY * 80 * ID);
    cast_dtw_k<<<(NLAY * ID * 64 + 255) / 256, blk, 0, stream>>>(dt_w, dwwf);
    if (full)
        cast_f16_k<<<cgrid(NLAY * 2 * ID * HD), blk, 0, stream>>>(
            in_proj_w, ipwf, NLAY * 2 * ID * HD);

    // ---- input MLP ----
    gemm_k<<<dim3(4, 64), blk, 0, stream>>>(
        x, DIN, mlp_in_w1, mlp_in_b1, nullptr, 0, h1b, 256, BL, 256, DIN, 1);
    hgemm64_k<<<dim3(4, 64), blk, 0, stream>>>(
        h1b, 256, w2f, 256, mlp_in_b2, nullptr, 0, nullptr, 0, h2b, 256, 256,
        BL, 256, 256, 1);
    hgemm64_k<<<dim3(12, 64), blk, 0, stream>>>(
        h2b, 256, w3f, 256, mlp_in_b3, nullptr, 0, h, HD, nullptr, 0, 0,
        BL, HD, 256, 0);

    for (int l = 0; l < NLAY; ++l) {
        const float* nw  = norm_w + (size_t)l * HD;
        const float* cw  = conv_w + (size_t)l * ID * KD;
        const float* cb  = conv_b + (size_t)l * ID;
        const float* db  = dt_b   + (size_t)l * ID;
        const float* al  = A_log  + (size_t)l * ID * ND;
        const float* dv  = Dp     + (size_t)l * ID;

        const f16* ipw;
        if (full) {
            ipw = ipwf + (size_t)l * 2 * ID * HD;
        } else {
            cast_f16_k<<<cgrid(2 * ID * HD), blk, 0, stream>>>(
                in_proj_w + (size_t)l * 2 * ID * HD, ipwf, 2 * ID * HD);
            ipw = ipwf;
        }
        rmsnorm_k<<<BL, blk, 0, stream>>>(h, nw, hnb);
        hgemm_k<<<dim3(24, 32), blk, 0, stream>>>(
            hnb, HD, ipw, HD, nullptr, nullptr, 0, nullptr, 0,
            projb, 2 * ID, 2 * ID, BL, 2 * ID, HD, 0);
        conv_silu_k<<<(BL * (ID / 8) + 255) / 256, blk, 0, stream>>>(
            projb, cw, cb, ub);

        hgemm64s_k<<<dim3(2, 64, 4), blk, 0, stream>>>(
            ub, ID, xpwf + (size_t)l * 80 * ID, ID,
            xpart, 80, (size_t)BL * 80, 80, ID / 4);
        xcomb_k<<<(BL * 96 + 255) / 256, blk, 0, stream>>>(xpart, ssm, ssmb);

        hgemm64_k<<<dim3(24, 64), blk, 0, stream>>>(
            ssmb, 64, dwwf + (size_t)l * ID * 64, 64, db, nullptr, 0,
            nullptr, 0, dtf, ID, ID, BL, ID, 64, 3);

        scan1_k<<<dim3(ID / 256, NC, BB), blk, 0, stream>>>(
            dtf, ssm, ub, al, Pw, Hw);
        scan_comb_k<<<(BB * ID * 16) / 256, blk, 0, stream>>>(Pw, Hw);
        scan2_k<<<dim3(ID / 256, NC, BB), blk, 0, stream>>>(
            dtf, ssm, ub, projb, al, dv, Hw, ybb);

        hgemm64_k<<<dim3(12, 64), blk, 0, stream>>>(
            ybb, ID, opwf + (size_t)l * HD * ID, ID, nullptr, h, HD,
            h, HD, nullptr, 0, 0, BL, HD, ID, 0);
    }

    // ---- final norm + attention pooling ----
    rmsnorm_k<<<BL, blk, 0, stream>>>(h, norm_f_w, hnb);
    hgemm64_k<<<dim3(2, 64), blk, 0, stream>>>(
        hnb, HD, a1f, HD, nullptr, nullptr, 0, h1a, DA_, nullptr, 0, 0,
        BL, DA_, HD, 2);
    gemm_k<<<dim3(1, 64), blk, 0, stream>>>(
        h1a, DA_, attn_ws2, nullptr, sbuf, RP_, nullptr, 0, BL, RP_, DA_, 0);
    softmax_k<<<BB * RP_, blk, 0, stream>>>(sbuf, attn);
    zero_k<<<(BB * RP_ * HD + 255) / 256, blk, 0, stream>>>(mbuf, BB * RP_ * HD);
    pool_k<<<dim3(BB * RP_, LL / 64), blk, 0, stream>>>(attn, hnb, mbuf);

    // ---- output MLP ----
    gemv_k<<<dim3(256, BB), dim3(64), 0, stream>>>(
        mbuf, RP_ * HD, mlp_out_w1, mlp_out_b1, o1, 256, RP_ * HD, 1);
    gemv_k<<<dim3(256, BB), dim3(64), 0, stream>>>(
        o1, 256, mlp_out_w2, mlp_out_b2, o2, 256, 256, 1);
    gemv_k<<<dim3(1, BB), dim3(64), 0, stream>>>(
        o2, 256, mlp_out_w3, mlp_out_b3, out, 1, 256, 0);
}

// Round 9
// 2054.494 us; speedup vs baseline: 1.0948x; 1.0948x over previous
//
#include <hip/hip_runtime.h>
#include <cstddef>
#include <cstdint>

// Model dims
#define HD    768
#define ID    1536
#define ND    16
#define KD    4
#define RD    48
#define NLAY  8
#define BB    4
#define LL    1024
#define BL    4096   // BB*LL
#define DIN   13
#define DA_   128
#define RP_   4

// scan chunking
#define NC    32
#define CS    32     // LL/NC

typedef _Float16 f16;
typedef f16 f16x8 __attribute__((ext_vector_type(8)));
typedef float f32x4 __attribute__((ext_vector_type(4)));

__device__ __forceinline__ float softplus_f(float x) {
    return (x > 20.f) ? x : log1pf(expf(x));
}

__device__ __forceinline__ float fast_exp2(float x) {
#if __has_builtin(__builtin_amdgcn_exp2f)
    return __builtin_amdgcn_exp2f(x);
#else
    return exp2f(x);
#endif
}

// ---------------- fp32 -> f16 cast ----------------
__global__ __launch_bounds__(256) void cast_f16_k(
    const float* __restrict__ in, f16* __restrict__ out, int n)
{
    int i = (blockIdx.x * 256 + threadIdx.x) * 4;
    if (i + 3 < n) {
        float4 v = *(const float4*)(in + i);
        out[i]     = (f16)v.x;
        out[i + 1] = (f16)v.y;
        out[i + 2] = (f16)v.z;
        out[i + 3] = (f16)v.w;
    } else {
        for (int j = i; j < n; ++j) out[j] = (f16)in[j];
    }
}

// dt_w (NL*1536 rows of 48) -> padded (rows of 64, zeros at k>=48)
__global__ __launch_bounds__(256) void cast_dtw_k(
    const float* __restrict__ in, f16* __restrict__ out)
{
    int idx = blockIdx.x * 256 + threadIdx.x;
    if (idx >= NLAY * ID * 64) return;
    int k = idx & 63, r = idx >> 6;
    out[idx] = (k < RD) ? (f16)in[r * RD + k] : (f16)0.f;
}

// ---------------- zero fill ----------------
__global__ __launch_bounds__(256) void zero_k(float* __restrict__ p, int n)
{
    int i = blockIdx.x * 256 + threadIdx.x;
    if (i < n) p[i] = 0.f;
}

// ---------------- epilogue helper ----------------
__device__ __forceinline__ void epilogue_store(
    float v, int row, int col, int N,
    const float* __restrict__ res, int ldres,
    float* __restrict__ C, int ldc,
    f16* __restrict__ Cb, int ldcb, int ncb, int act,
    const float* __restrict__ bias)
{
    if (col >= N) return;
    if (bias) v += bias[col];
    if (act == 1) v = fmaxf(v, 0.f);
    else if (act == 2) v = tanhf(v);
    else if (act == 3) v = softplus_f(v);
    if (res) v += res[(size_t)row * ldres + col];
    if (C) C[(size_t)row * ldc + col] = v;
    if (Cb && col < ncb) Cb[(size_t)row * ldcb + col] = (f16)v;
}

__device__ __forceinline__ void async_copy16(const f16* g, f16* l) {
    __builtin_amdgcn_global_load_lds(
        (const __attribute__((address_space(1))) void*)g,
        (__attribute__((address_space(3))) void*)l, 16, 0, 0);
}

// ---------------- f16 MFMA GEMM, 128x128 tile, BK=32, two-barrier ----------
// R5's proven best for in_proj (62 us / 312 TF). Do NOT dbuf (R8 regression).
__global__ __launch_bounds__(256) void hgemm_k(
    const f16* __restrict__ A, int lda,
    const f16* __restrict__ W, int ldw,
    const float* __restrict__ bias,
    const float* __restrict__ res, int ldres,
    float* __restrict__ C, int ldc,
    f16* __restrict__ Cb, int ldcb, int ncb,
    int M, int N, int K, int act)
{
    __shared__ f16 As[128 * 32];
    __shared__ f16 Bs[128 * 32];
    int tid = threadIdx.x;
    int wave = tid >> 6, lane = tid & 63;
    int m0 = blockIdx.y * 128, n0 = blockIdx.x * 128;

    int wm = wave & 1, wn = wave >> 1;
    int lm = lane & 15;
    int kq = (lane >> 4) * 8;

    int srow = lane >> 2;
    int skc  = (lane & 3) * 8;

    f32x4 acc[4][4] = {};

    for (int k0 = 0; k0 < K; k0 += 32) {
#pragma unroll
        for (int it = 0; it < 2; ++it) {
            int c16 = wave + it * 4;
            int row = c16 * 16 + srow;
            const f16* ga = A + (size_t)(m0 + row) * lda + k0 + skc;
            const f16* gb = W + (size_t)(n0 + row) * ldw + k0 + skc;
            async_copy16(ga, As + c16 * 512);
            async_copy16(gb, Bs + c16 * 512);
        }
        __syncthreads();

        f16x8 af[4], bf[4];
#pragma unroll
        for (int mt = 0; mt < 4; ++mt)
            af[mt] = *(const f16x8*)(As + (wm * 64 + mt * 16 + lm) * 32 + kq);
#pragma unroll
        for (int nt = 0; nt < 4; ++nt)
            bf[nt] = *(const f16x8*)(Bs + (wn * 64 + nt * 16 + lm) * 32 + kq);
#pragma unroll
        for (int mt = 0; mt < 4; ++mt)
#pragma unroll
            for (int nt = 0; nt < 4; ++nt)
                acc[mt][nt] = __builtin_amdgcn_mfma_f32_16x16x32_f16(
                    af[mt], bf[nt], acc[mt][nt], 0, 0, 0);
        __syncthreads();
    }

    int rq = (lane >> 4) * 4;
#pragma unroll
    for (int mt = 0; mt < 4; ++mt)
#pragma unroll
        for (int nt = 0; nt < 4; ++nt) {
            int col = n0 + wn * 64 + nt * 16 + lm;
#pragma unroll
            for (int r = 0; r < 4; ++r) {
                int row = m0 + wm * 64 + mt * 16 + rq + r;
                epilogue_store(acc[mt][nt][r], row, col, N, res, ldres,
                               C, ldc, Cb, ldcb, ncb, act, bias);
            }
        }
}

// ---------------- f16 MFMA GEMM, 64x64 tile, BK=64, two-barrier ------------
__global__ __launch_bounds__(256) void hgemm64_k(
    const f16* __restrict__ A, int lda,
    const f16* __restrict__ W, int ldw,
    const float* __restrict__ bias,
    const float* __restrict__ res, int ldres,
    float* __restrict__ C, int ldc,
    f16* __restrict__ Cb, int ldcb, int ncb,
    int M, int N, int K, int act)
{
    __shared__ f16 As[64 * 64];
    __shared__ f16 Bs[64 * 64];
    int tid = threadIdx.x;
    int wave = tid >> 6, lane = tid & 63;
    int m0 = blockIdx.y * 64, n0 = blockIdx.x * 64;

    int wm = wave & 1, wn = wave >> 1;
    int lm = lane & 15;
    int kq = (lane >> 4) * 8;

    int srow = tid >> 2;          // 0..63
    int skc  = (tid & 3) * 8;

    f32x4 acc[2][2] = {};

    for (int k0 = 0; k0 < K; k0 += 64) {
#pragma unroll
        for (int it = 0; it < 2; ++it) {
            int kk   = it * 32 + skc;
            int base = it * 2048 + wave * 512;
            async_copy16(A + (size_t)(m0 + srow) * lda + k0 + kk, As + base);
            async_copy16(W + (size_t)(n0 + srow) * ldw + k0 + kk, Bs + base);
        }
        __syncthreads();

        f16x8 af[2][2], bf[2][2];
#pragma unroll
        for (int ks = 0; ks < 2; ++ks) {
#pragma unroll
            for (int mt = 0; mt < 2; ++mt)
                af[mt][ks] = *(const f16x8*)(As + ks * 2048 +
                                 (wm * 32 + mt * 16 + lm) * 32 + kq);
#pragma unroll
            for (int nt = 0; nt < 2; ++nt)
                bf[nt][ks] = *(const f16x8*)(Bs + ks * 2048 +
                                 (wn * 32 + nt * 16 + lm) * 32 + kq);
        }
#pragma unroll
        for (int ks = 0; ks < 2; ++ks)
#pragma unroll
            for (int mt = 0; mt < 2; ++mt)
#pragma unroll
                for (int nt = 0; nt < 2; ++nt)
                    acc[mt][nt] = __builtin_amdgcn_mfma_f32_16x16x32_f16(
                        af[mt][ks], bf[nt][ks], acc[mt][nt], 0, 0, 0);
        __syncthreads();
    }

    int rq = (lane >> 4) * 4;
#pragma unroll
    for (int mt = 0; mt < 2; ++mt)
#pragma unroll
        for (int nt = 0; nt < 2; ++nt) {
            int col = n0 + wn * 32 + nt * 16 + lm;
#pragma unroll
            for (int r = 0; r < 4; ++r) {
                int row = m0 + wm * 32 + mt * 16 + rq + r;
                epilogue_store(acc[mt][nt][r], row, col, N, res, ldres,
                               C, ldc, Cb, ldcb, ncb, act, bias);
            }
        }
}

// ---------------- x_proj split-K GEMM: 64x64 tile, fp32 partial out --------
__global__ __launch_bounds__(256) void hgemm64s_k(
    const f16* __restrict__ A, int lda,
    const f16* __restrict__ W, int ldw,
    float* __restrict__ Cp, int ldc, size_t PS,
    int N, int kPer)
{
    __shared__ f16 As[64 * 64];
    __shared__ f16 Bs[64 * 64];
    int tid = threadIdx.x;
    int wave = tid >> 6, lane = tid & 63;
    int m0 = blockIdx.y * 64, n0 = blockIdx.x * 64;
    int z = blockIdx.z;
    int kbeg = z * kPer, kend = kbeg + kPer;

    int wm = wave & 1, wn = wave >> 1;
    int lm = lane & 15;
    int kq = (lane >> 4) * 8;
    int srow = tid >> 2;
    int skc  = (tid & 3) * 8;

    f32x4 acc[2][2] = {};

    for (int k0 = kbeg; k0 < kend; k0 += 64) {
#pragma unroll
        for (int it = 0; it < 2; ++it) {
            int kk   = it * 32 + skc;
            int base = it * 2048 + wave * 512;
            async_copy16(A + (size_t)(m0 + srow) * lda + k0 + kk, As + base);
            async_copy16(W + (size_t)(n0 + srow) * ldw + k0 + kk, Bs + base);
        }
        __syncthreads();

        f16x8 af[2][2], bf[2][2];
#pragma unroll
        for (int ks = 0; ks < 2; ++ks) {
#pragma unroll
            for (int mt = 0; mt < 2; ++mt)
                af[mt][ks] = *(const f16x8*)(As + ks * 2048 +
                                 (wm * 32 + mt * 16 + lm) * 32 + kq);
#pragma unroll
            for (int nt = 0; nt < 2; ++nt)
                bf[nt][ks] = *(const f16x8*)(Bs + ks * 2048 +
                                 (wn * 32 + nt * 16 + lm) * 32 + kq);
        }
#pragma unroll
        for (int ks = 0; ks < 2; ++ks)
#pragma unroll
            for (int mt = 0; mt < 2; ++mt)
#pragma unroll
                for (int nt = 0; nt < 2; ++nt)
                    acc[mt][nt] = __builtin_amdgcn_mfma_f32_16x16x32_f16(
                        af[mt][ks], bf[nt][ks], acc[mt][nt], 0, 0, 0);
        __syncthreads();
    }

    float* C = Cp + (size_t)z * PS;
    int rq = (lane >> 4) * 4;
#pragma unroll
    for (int mt = 0; mt < 2; ++mt)
#pragma unroll
        for (int nt = 0; nt < 2; ++nt) {
            int col = n0 + wn * 32 + nt * 16 + lm;
            if (col >= N) continue;
#pragma unroll
            for (int r = 0; r < 4; ++r) {
                int row = m0 + wm * 32 + mt * 16 + rq + r;
                C[(size_t)row * ldc + col] = acc[mt][nt][r];
            }
        }
}

// combine 4 x_proj partials -> ssm fp32 + ssmb f16 (48 cols + 16 zero pad)
__global__ __launch_bounds__(256) void xcomb_k(
    const float* __restrict__ part, float* __restrict__ ssm,
    f16* __restrict__ ssmb)
{
    int idx = blockIdx.x * 256 + threadIdx.x;   // over BL*96
    if (idx >= BL * 96) return;
    int row = idx / 96, c = idx % 96;
    const size_t PS = (size_t)BL * 80;
    if (c < 80) {
        size_t o = (size_t)row * 80 + c;
        float s = part[o] + part[PS + o] + part[2 * PS + o] + part[3 * PS + o];
        ssm[o] = s;
        if (c < RD) ssmb[(size_t)row * 64 + c] = (f16)s;
    } else {
        ssmb[(size_t)row * 64 + (c - 80 + RD)] = (f16)0.f;
    }
}

// ---------------- fp32 tiled GEMM (small-K cases) ----------------
#define BM 64
#define BN 64
#define BKK 16
__global__ __launch_bounds__(256) void gemm_k(
    const float* __restrict__ A, int lda,
    const float* __restrict__ W,
    const float* __restrict__ bias,
    float* __restrict__ C, int ldc,
    f16* __restrict__ Cb, int ldcb,
    int M, int N, int K, int act)
{
    __shared__ float As[BKK][BM + 4];
    __shared__ float Ws[BKK][BN + 4];
    int tid = threadIdx.x;
    int tx = tid & 15, ty = tid >> 4;
    int m0 = blockIdx.y * BM, n0 = blockIdx.x * BN;
    float acc[4][4] = {};
    int arow = tid >> 2;
    int acol = (tid & 3) * 4;

    for (int k0 = 0; k0 < K; k0 += BKK) {
        int gm = m0 + arow;
        int gn = n0 + arow;
#pragma unroll
        for (int j = 0; j < 4; ++j) {
            int gk = k0 + acol + j;
            float av = 0.f, wv = 0.f;
            if (gm < M && gk < K) av = A[(size_t)gm * lda + gk];
            if (gn < N && gk < K) wv = W[(size_t)gn * K + gk];
            As[acol + j][arow] = av;
            Ws[acol + j][arow] = wv;
        }
        __syncthreads();
#pragma unroll
        for (int k = 0; k < BKK; ++k) {
            float a[4], b[4];
#pragma unroll
            for (int i = 0; i < 4; ++i) a[i] = As[k][ty * 4 + i];
#pragma unroll
            for (int j = 0; j < 4; ++j) b[j] = Ws[k][tx * 4 + j];
#pragma unroll
            for (int i = 0; i < 4; ++i)
#pragma unroll
                for (int j = 0; j < 4; ++j)
                    acc[i][j] += a[i] * b[j];
        }
        __syncthreads();
    }

#pragma unroll
    for (int i = 0; i < 4; ++i) {
        int row = m0 + ty * 4 + i;
        if (row >= M) continue;
#pragma unroll
        for (int j = 0; j < 4; ++j) {
            int col = n0 + tx * 4 + j;
            if (col >= N) continue;
            float v = acc[i][j];
            if (bias) v += bias[col];
            if (act == 1) v = fmaxf(v, 0.f);
            if (C) C[(size_t)row * ldc + col] = v;
            if (Cb) Cb[(size_t)row * ldcb + col] = (f16)v;
        }
    }
}

// ---------------- RMSNorm over 768, f16 out ----------------
__global__ __launch_bounds__(256) void rmsnorm_k(
    const float* __restrict__ x, const float* __restrict__ w,
    f16* __restrict__ out)
{
    int row = blockIdx.x;
    const float* xr = x + (size_t)row * HD;
    int tid = threadIdx.x;
    float v0 = xr[tid], v1 = xr[tid + 256], v2 = xr[tid + 512];
    __shared__ float red[256];
    red[tid] = v0 * v0 + v1 * v1 + v2 * v2;
    __syncthreads();
    for (int o = 128; o; o >>= 1) {
        if (tid < o) red[tid] += red[tid + o];
        __syncthreads();
    }
    float scale = rsqrtf(red[0] / (float)HD + 1e-5f);
    f16* outr = out + (size_t)row * HD;
    outr[tid]       = (f16)(v0 * scale * w[tid]);
    outr[tid + 256] = (f16)(v1 * scale * w[tid + 256]);
    outr[tid + 512] = (f16)(v2 * scale * w[tid + 512]);
}

// ---------------- Causal depthwise conv (K=4) + bias + SiLU, x8 vector ------
__global__ __launch_bounds__(256) void conv_silu_k(
    const f16* __restrict__ projb, const float* __restrict__ cw,
    const float* __restrict__ cb, f16* __restrict__ ub)
{
    int idx = blockIdx.x * 256 + threadIdx.x;   // over BL*ID/8
    if (idx >= BL * (ID / 8)) return;
    int i8  = (idx % (ID / 8)) * 8;
    int row = idx / (ID / 8);
    int t = row & (LL - 1);

    float4 wv[8];
#pragma unroll
    for (int j = 0; j < 8; ++j)
        wv[j] = *(const float4*)(cw + (i8 + j) * KD);

    float s[8];
    float4 cb0 = *(const float4*)(cb + i8);
    float4 cb1 = *(const float4*)(cb + i8 + 4);
    s[0] = cb0.x; s[1] = cb0.y; s[2] = cb0.z; s[3] = cb0.w;
    s[4] = cb1.x; s[5] = cb1.y; s[6] = cb1.z; s[7] = cb1.w;

#pragma unroll
    for (int k = 0; k < KD; ++k) {
        int tt = t - (KD - 1) + k;
        if (tt < 0) continue;
        f16x8 p = *(const f16x8*)(projb + (size_t)(row - (KD - 1) + k) * (2 * ID) + i8);
#pragma unroll
        for (int j = 0; j < 8; ++j) {
            float wk = (k == 0) ? wv[j].x : (k == 1) ? wv[j].y
                     : (k == 2) ? wv[j].z : wv[j].w;
            s[j] += (float)p[j] * wk;
        }
    }
    f16x8 o;
#pragma unroll
    for (int j = 0; j < 8; ++j) {
        float v = s[j] / (1.f + expf(-s[j]));
        o[j] = (f16)v;
    }
    *(f16x8*)(ub + (size_t)row * ID + i8) = o;
}

// ---------------- Selective scan: chunked two-pass ----------------
__global__ __launch_bounds__(256) void scan1_k(
    const f16*   __restrict__ dtf,   // (BL,ID)
    const float* __restrict__ ssm,   // (BL,80): B at +48
    const f16*   __restrict__ ub,    // (BL,ID)
    const float* __restrict__ A_log, // (ID,16)
    float* __restrict__ Pw, float* __restrict__ Hw)
{
    int b = blockIdx.z, c = blockIdx.y;
    int i = blockIdx.x * 256 + threadIdx.x;
    __shared__ float sB[CS * 16];
    for (int idx = threadIdx.x; idx < CS * 16; idx += 256) {
        int t = idx >> 4, n = idx & 15;
        sB[idx] = ssm[((size_t)(b * LL + c * CS + t)) * 80 + 48 + n];
    }
    __syncthreads();

    float Ain[16];
#pragma unroll
    for (int n = 0; n < 16; ++n)
        Ain[n] = -expf(A_log[i * ND + n]) * 1.44269504f;

    float h[16];
    float sdt = 0.f;
#pragma unroll
    for (int n = 0; n < 16; ++n) h[n] = 0.f;

    for (int t = 0; t < CS; ++t) {
        size_t row = (size_t)(b * LL + c * CS + t);
        float dtv = (float)dtf[row * ID + i];
        float x = dtv * (float)ub[row * ID + i];
        sdt += dtv;
        const float4* Bv = (const float4*)(sB + t * 16);
        float4 B0 = Bv[0], B1 = Bv[1], B2 = Bv[2], B3 = Bv[3];
        float Bf[16] = {B0.x, B0.y, B0.z, B0.w, B1.x, B1.y, B1.z, B1.w,
                        B2.x, B2.y, B2.z, B2.w, B3.x, B3.y, B3.z, B3.w};
#pragma unroll
        for (int n = 0; n < 16; ++n) {
            float dA = fast_exp2(dtv * Ain[n]);
            h[n] = dA * h[n] + x * Bf[n];
        }
    }
    size_t off = (((size_t)(b * NC + c) * ID + i) << 4);
    float4* pw = (float4*)(Pw + off);
    float4* hw = (float4*)(Hw + off);
#pragma unroll
    for (int q = 0; q < 4; ++q) {
        pw[q] = make_float4(fast_exp2(sdt * Ain[q*4]),
                            fast_exp2(sdt * Ain[q*4+1]),
                            fast_exp2(sdt * Ain[q*4+2]),
                            fast_exp2(sdt * Ain[q*4+3]));
        hw[q] = make_float4(h[q*4], h[q*4+1], h[q*4+2], h[q*4+3]);
    }
}

__global__ __launch_bounds__(256) void scan_comb_k(
    const float* __restrict__ Pw, float* __restrict__ Hw)
{
    int idx = blockIdx.x * 256 + threadIdx.x;   // over BB*ID*16
    int rem = idx & (ID * 16 - 1);
    int b = idx / (ID * 16);
    size_t base = (size_t)b * NC * ID * 16 + rem;
    float e = 0.f;
    for (int c = 0; c < NC; ++c) {
        size_t off = base + (size_t)c * ID * 16;
        float Hc = Hw[off];
        float Pc = Pw[off];
        Hw[off] = e;
        e = Hc + Pc * e;
    }
}

__global__ __launch_bounds__(256) void scan2_k(
    const f16*   __restrict__ dtf,
    const float* __restrict__ ssm,   // B at +48, C at +64
    const f16*   __restrict__ ub,
    const f16*   __restrict__ projb, // gate at +ID
    const float* __restrict__ A_log,
    const float* __restrict__ D,
    const float* __restrict__ Hw,    // entry states
    f16* __restrict__ y)
{
    int b = blockIdx.z, c = blockIdx.y;
    int i = blockIdx.x * 256 + threadIdx.x;
    __shared__ float sB[CS * 16];
    __shared__ float sC[CS * 16];
    for (int idx = threadIdx.x; idx < CS * 16; idx += 256) {
        int t = idx >> 4, n = idx & 15;
        size_t row = (size_t)(b * LL + c * CS + t);
        sB[idx] = ssm[row * 80 + 48 + n];
        sC[idx] = ssm[row * 80 + 64 + n];
    }
    __syncthreads();

    float Ain[16];
#pragma unroll
    for (int n = 0; n < 16; ++n)
        Ain[n] = -expf(A_log[i * ND + n]) * 1.44269504f;
    float Dv = D[i];

    float h[16];
    size_t off = (((size_t)(b * NC + c) * ID + i) << 4);
    const float4* hw = (const float4*)(Hw + off);
#pragma unroll
    for (int q = 0; q < 4; ++q) {
        float4 v = hw[q];
        h[q*4] = v.x; h[q*4+1] = v.y; h[q*4+2] = v.z; h[q*4+3] = v.w;
    }

    for (int t = 0; t < CS; ++t) {
        size_t row = (size_t)(b * LL + c * CS + t);
        float dtv = (float)dtf[row * ID + i];
        float uv  = (float)ub[row * ID + i];
        float g   = (float)projb[row * (2 * ID) + ID + i];
        float x = dtv * uv;
        const float4* Bv = (const float4*)(sB + t * 16);
        const float4* Cv = (const float4*)(sC + t * 16);
        float4 B0 = Bv[0], B1 = Bv[1], B2 = Bv[2], B3 = Bv[3];
        float4 C0 = Cv[0], C1 = Cv[1], C2 = Cv[2], C3 = Cv[3];
        float Bf[16] = {B0.x, B0.y, B0.z, B0.w, B1.x, B1.y, B1.z, B1.w,
                        B2.x, B2.y, B2.z, B2.w, B3.x, B3.y, B3.z, B3.w};
        float Cf[16] = {C0.x, C0.y, C0.z, C0.w, C1.x, C1.y, C1.z, C1.w,
                        C2.x, C2.y, C2.z, C2.w, C3.x, C3.y, C3.z, C3.w};
        float yv = 0.f;
#pragma unroll
        for (int n = 0; n < 16; ++n) {
            float dA = fast_exp2(dtv * Ain[n]);
            h[n] = dA * h[n] + x * Bf[n];
            yv += h[n] * Cf[n];
        }
        yv = (yv + uv * Dv) * (g / (1.f + expf(-g)));
        y[row * ID + i] = (f16)yv;
    }
}

// ---------------- Softmax over L per (b,r) ----------------
__global__ __launch_bounds__(256) void softmax_k(
    const float* __restrict__ s, float* __restrict__ attn)
{
    int b = blockIdx.x >> 2, r = blockIdx.x & 3;
    int tid = threadIdx.x;
    __shared__ float red[256];
    float mx = -1e30f;
    for (int j = 0; j < 4; ++j) {
        int t = tid + j * 256;
        mx = fmaxf(mx, s[((size_t)(b * LL + t)) * RP_ + r]);
    }
    red[tid] = mx;
    __syncthreads();
    for (int o = 128; o; o >>= 1) {
        if (tid < o) red[tid] = fmaxf(red[tid], red[tid + o]);
        __syncthreads();
    }
    mx = red[0];
    __syncthreads();
    float ev[4], sum = 0.f;
    for (int j = 0; j < 4; ++j) {
        int t = tid + j * 256;
        ev[j] = expf(s[((size_t)(b * LL + t)) * RP_ + r] - mx);
        sum += ev[j];
    }
    red[tid] = sum;
    __syncthreads();
    for (int o = 128; o; o >>= 1) {
        if (tid < o) red[tid] += red[tid + o];
        __syncthreads();
    }
    float inv = 1.f / red[0];
    for (int j = 0; j < 4; ++j) {
        int t = tid + j * 256;
        attn[((size_t)(b * LL + t)) * RP_ + r] = ev[j] * inv;
    }
}

// ---------------- attn pool: chunk-parallel + atomics ----------------
__global__ __launch_bounds__(256) void pool_k(
    const float* __restrict__ attn, const f16* __restrict__ hn,
    float* __restrict__ m)
{
    int br = blockIdx.x;
    int b = br >> 2, r = br & 3;
    int t0 = blockIdx.y * 64;
    int tid = threadIdx.x;
    float acc0 = 0.f, acc1 = 0.f, acc2 = 0.f;
    for (int t = t0; t < t0 + 64; ++t) {
        float w = attn[((size_t)(b * LL + t)) * RP_ + r];
        const f16* hr = hn + ((size_t)(b * LL + t)) * HD;
        acc0 += w * (float)hr[tid];
        acc1 += w * (float)hr[tid + 256];
        acc2 += w * (float)hr[tid + 512];
    }
    float* outp = m + ((size_t)(b * RP_ + r)) * HD;
    atomicAdd(outp + tid, acc0);
    atomicAdd(outp + tid + 256, acc1);
    atomicAdd(outp + tid + 512, acc2);
}

// ---------------- small GEMV ----------------
__global__ __launch_bounds__(64) void gemv_k(
    const float* __restrict__ A, int lda,
    const float* __restrict__ W, const float* __restrict__ bias,
    float* __restrict__ C, int ldc, int K, int relu)
{
    int n = blockIdx.x, b = blockIdx.y;
    int lane = threadIdx.x;
    const float* a = A + (size_t)b * lda;
    const float* w = W + (size_t)n * K;
    float s = 0.f;
    for (int k = lane; k < K; k += 64) s += a[k] * w[k];
    for (int off = 32; off; off >>= 1) s += __shfl_down(s, off);
    if (lane == 0) {
        float v = s + (bias ? bias[n] : 0.f);
        if (relu) v = fmaxf(v, 0.f);
        C[(size_t)b * ldc + n] = v;
    }
}

extern "C" void kernel_launch(void* const* d_in, const int* in_sizes, int n_in,
                              void* d_out, int out_size, void* d_ws, size_t ws_size,
                              hipStream_t stream) {
    const float* x          = (const float*)d_in[0];
    const float* mlp_in_w1  = (const float*)d_in[1];
    const float* mlp_in_b1  = (const float*)d_in[2];
    const float* mlp_in_w2  = (const float*)d_in[3];
    const float* mlp_in_b2  = (const float*)d_in[4];
    const float* mlp_in_w3  = (const float*)d_in[5];
    const float* mlp_in_b3  = (const float*)d_in[6];
    const float* norm_w     = (const float*)d_in[7];
    const float* in_proj_w  = (const float*)d_in[8];
    const float* conv_w     = (const float*)d_in[9];
    const float* conv_b     = (const float*)d_in[10];
    const float* x_proj_w   = (const float*)d_in[11];
    const float* dt_w       = (const float*)d_in[12];
    const float* dt_b       = (const float*)d_in[13];
    const float* A_log      = (const float*)d_in[14];
    const float* Dp         = (const float*)d_in[15];
    const float* out_proj_w = (const float*)d_in[16];
    const float* norm_f_w   = (const float*)d_in[17];
    const float* attn_ws1   = (const float*)d_in[18];
    const float* attn_ws2   = (const float*)d_in[19];
    const float* mlp_out_w1 = (const float*)d_in[20];
    const float* mlp_out_b1 = (const float*)d_in[21];
    const float* mlp_out_w2 = (const float*)d_in[22];
    const float* mlp_out_b2 = (const float*)d_in[23];
    const float* mlp_out_w3 = (const float*)d_in[24];
    const float* mlp_out_b3 = (const float*)d_in[25];
    float* out = (float*)d_out;

    // ---- workspace layout ----
    float* ws    = (float*)d_ws;
    float* h     = ws;                        // 4096*768
    float* ssm   = h    + (size_t)BL * HD;    // 4096*80
    float* xpart = ssm  + (size_t)BL * 80;    // 4 * 4096*80
    float* h1a   = xpart+ (size_t)4 * BL * 80;// 4096*128
    float* sbuf  = h1a  + (size_t)BL * DA_;   // 4096*4
    float* attn  = sbuf + (size_t)BL * 4;     // 4096*4
    float* mbuf  = attn + (size_t)BL * 4;     // 4*4*768
    float* o1    = mbuf + (size_t)BB * RP_ * HD;
    float* o2    = o1   + (size_t)BB * 256;
    float* Pw    = o2   + (size_t)BB * 256;   // 4*32*1536*16
    float* Hw    = Pw   + (size_t)BB * NC * ID * 16;
    f16* fb    = (f16*)(Hw + (size_t)BB * NC * ID * 16);
    f16* h1b   = fb;                          // 4096*256
    f16* h2b   = h1b  + (size_t)BL * 256;     // 4096*256
    f16* hnb   = h2b  + (size_t)BL * 256;     // 4096*768
    f16* projb = hnb  + (size_t)BL * HD;      // 4096*3072
    f16* ub    = projb+ (size_t)BL * 2 * ID;  // 4096*1536
    f16* ssmb  = ub   + (size_t)BL * ID;      // 4096*64
    f16* dtf   = ssmb + (size_t)BL * 64;      // 4096*1536
    f16* ybb   = dtf  + (size_t)BL * ID;      // 4096*1536
    f16* opwf  = ybb  + (size_t)BL * ID;      // 8*768*1536
    f16* xpwf  = opwf + (size_t)NLAY * HD * ID;
    f16* dwwf  = xpwf + (size_t)NLAY * 80 * ID;
    f16* w2f   = dwwf + (size_t)NLAY * ID * 64;
    f16* w3f   = w2f  + 256 * 256;
    f16* a1f   = w3f  + HD * 256;
    f16* ipwf  = a1f  + DA_ * HD;             // 1 or 8 slots, LAST

    size_t used_bytes = (size_t)((char*)(ipwf) - (char*)d_ws);
    size_t slot_bytes = (size_t)2 * ID * HD * sizeof(f16);
    int full = (ws_size >= used_bytes + (size_t)NLAY * slot_bytes) ? 1 : 0;

    dim3 blk(256);
    auto cgrid = [](int n) { return dim3((n / 4 + 255) / 256); };

    // ---- weight casts ----
    cast_f16_k<<<cgrid(256 * 256), blk, 0, stream>>>(mlp_in_w2, w2f, 256 * 256);
    cast_f16_k<<<cgrid(HD * 256), blk, 0, stream>>>(mlp_in_w3, w3f, HD * 256);
    cast_f16_k<<<cgrid(DA_ * HD), blk, 0, stream>>>(attn_ws1, a1f, DA_ * HD);
    cast_f16_k<<<cgrid(NLAY * HD * ID), blk, 0, stream>>>(out_proj_w, opwf, NLAY * HD * ID);
    cast_f16_k<<<cgrid(NLAY * 80 * ID), blk, 0, stream>>>(x_proj_w, xpwf, NLAY * 80 * ID);
    cast_dtw_k<<<(NLAY * ID * 64 + 255) / 256, blk, 0, stream>>>(dt_w, dwwf);
    if (full)
        cast_f16_k<<<cgrid(NLAY * 2 * ID * HD), blk, 0, stream>>>(
            in_proj_w, ipwf, NLAY * 2 * ID * HD);

    // ---- input MLP ----
    gemm_k<<<dim3(4, 64), blk, 0, stream>>>(
        x, DIN, mlp_in_w1, mlp_in_b1, nullptr, 0, h1b, 256, BL, 256, DIN, 1);
    hgemm64_k<<<dim3(4, 64), blk, 0, stream>>>(
        h1b, 256, w2f, 256, mlp_in_b2, nullptr, 0, nullptr, 0, h2b, 256, 256,
        BL, 256, 256, 1);
    hgemm64_k<<<dim3(12, 64), blk, 0, stream>>>(
        h2b, 256, w3f, 256, mlp_in_b3, nullptr, 0, h, HD, nullptr, 0, 0,
        BL, HD, 256, 0);

    for (int l = 0; l < NLAY; ++l) {
        const float* nw  = norm_w + (size_t)l * HD;
        const float* cw  = conv_w + (size_t)l * ID * KD;
        const float* cb  = conv_b + (size_t)l * ID;
        const float* db  = dt_b   + (size_t)l * ID;
        const float* al  = A_log  + (size_t)l * ID * ND;
        const float* dv  = Dp     + (size_t)l * ID;

        const f16* ipw;
        if (full) {
            ipw = ipwf + (size_t)l * 2 * ID * HD;
        } else {
            cast_f16_k<<<cgrid(2 * ID * HD), blk, 0, stream>>>(
                in_proj_w + (size_t)l * 2 * ID * HD, ipwf, 2 * ID * HD);
            ipw = ipwf;
        }
        rmsnorm_k<<<BL, blk, 0, stream>>>(h, nw, hnb);
        hgemm_k<<<dim3(24, 32), blk, 0, stream>>>(
            hnb, HD, ipw, HD, nullptr, nullptr, 0, nullptr, 0,
            projb, 2 * ID, 2 * ID, BL, 2 * ID, HD, 0);
        conv_silu_k<<<(BL * (ID / 8) + 255) / 256, blk, 0, stream>>>(
            projb, cw, cb, ub);

        hgemm64s_k<<<dim3(2, 64, 4), blk, 0, stream>>>(
            ub, ID, xpwf + (size_t)l * 80 * ID, ID,
            xpart, 80, (size_t)BL * 80, 80, ID / 4);
        xcomb_k<<<(BL * 96 + 255) / 256, blk, 0, stream>>>(xpart, ssm, ssmb);

        hgemm64_k<<<dim3(24, 64), blk, 0, stream>>>(
            ssmb, 64, dwwf + (size_t)l * ID * 64, 64, db, nullptr, 0,
            nullptr, 0, dtf, ID, ID, BL, ID, 64, 3);

        scan1_k<<<dim3(ID / 256, NC, BB), blk, 0, stream>>>(
            dtf, ssm, ub, al, Pw, Hw);
        scan_comb_k<<<(BB * ID * 16) / 256, blk, 0, stream>>>(Pw, Hw);
        scan2_k<<<dim3(ID / 256, NC, BB), blk, 0, stream>>>(
            dtf, ssm, ub, projb, al, dv, Hw, ybb);

        hgemm64_k<<<dim3(12, 64), blk, 0, stream>>>(
            ybb, ID, opwf + (size_t)l * HD * ID, ID, nullptr, h, HD,
            h, HD, nullptr, 0, 0, BL, HD, ID, 0);
    }

    // ---- final norm + attention pooling ----
    rmsnorm_k<<<BL, blk, 0, stream>>>(h, norm_f_w, hnb);
    hgemm64_k<<<dim3(2, 64), blk, 0, stream>>>(
        hnb, HD, a1f, HD, nullptr, nullptr, 0, h1a, DA_, nullptr, 0, 0,
        BL, DA_, HD, 2);
    gemm_k<<<dim3(1, 64), blk, 0, stream>>>(
        h1a, DA_, attn_ws2, nullptr, sbuf, RP_, nullptr, 0, BL, RP_, DA_, 0);
    softmax_k<<<BB * RP_, blk, 0, stream>>>(sbuf, attn);
    zero_k<<<(BB * RP_ * HD + 255) / 256, blk, 0, stream>>>(mbuf, BB * RP_ * HD);
    pool_k<<<dim3(BB * RP_, LL / 64), blk, 0, stream>>>(attn, hnb, mbuf);

    // ---- output MLP ----
    gemv_k<<<dim3(256, BB), dim3(64), 0, stream>>>(
        mbuf, RP_ * HD, mlp_out_w1, mlp_out_b1, o1, 256, RP_ * HD, 1);
    gemv_k<<<dim3(256, BB), dim3(64), 0, stream>>>(
        o1, 256, mlp_out_w2, mlp_out_b2, o2, 256, 256, 1);
    gemv_k<<<dim3(1, BB), dim3(64), 0, stream>>>(
        o2, 256, mlp_out_w3, mlp_out_b3, out, 1, 256, 0);
}